// Round 9
// baseline (233.815 us; speedup 1.0000x reference)
//
#include <hip/hip_runtime.h>
#include <math.h>

// B=4, H=W=64, C=256, Ck=32, N=4096, M=B*N=16384
// ws: fg bf16 [16384][64] (f=cols0..31, g=cols32..63, g pre-scaled by log2e)
//   | hmt bf16 [4][256][4096] (channel-major)
//   | wT bf16 [576][256] (0..31 Wf^T, 32..63 Wg^T*log2e, 64..319 Wh^T, 320..575 Wv^T)
//   | lpart f32 [S][16384]
//   | obf bf16 [S][1<<22]  -- FRAGMENT-SWIZZLED: chunk = row16*8 + (col>>5),
//       element (row,col) at chunk*512 + ((col>>3)&3)*128 + (row&15)*8 + (col&7)

typedef unsigned short u16;
typedef __attribute__((ext_vector_type(8))) short  bf16x8;
typedef __attribute__((ext_vector_type(4))) float  f32x4;

__device__ inline u16 f2bf(float x) {
    unsigned u = __float_as_uint(x);
    unsigned r = (u + 0x7fffu + ((u >> 16) & 1u)) >> 16;
    return (u16)r;
}

__device__ inline float bf2f(short s) {
    return __uint_as_float(((unsigned)(u16)s) << 16);
}

__device__ inline bf16x8 cvt8(float4 a, float4 b) {
    bf16x8 r;
    r[0] = (short)f2bf(a.x); r[1] = (short)f2bf(a.y);
    r[2] = (short)f2bf(a.z); r[3] = (short)f2bf(a.w);
    r[4] = (short)f2bf(b.x); r[5] = (short)f2bf(b.y);
    r[6] = (short)f2bf(b.z); r[7] = (short)f2bf(b.w);
    return r;
}

#define ASYNC_CP16(gp, lp)                                                     \
    __builtin_amdgcn_global_load_lds(                                          \
        (const __attribute__((address_space(1))) void*)(gp),                   \
        (__attribute__((address_space(3))) void*)(lp), 16, 0, 0)

#define LOG2E 1.4426950408889634f

// ---------------------------------------------------------------------------
// prep: pack weights transposed to bf16.  wT[n][k], n = concat col index.
// ---------------------------------------------------------------------------
__global__ __launch_bounds__(256) void prep_w(
    const float* __restrict__ Wf, const float* __restrict__ Wg,
    const float* __restrict__ Wh, const float* __restrict__ Wv,
    u16* __restrict__ wT)
{
    const int n = blockIdx.x;
    const int k = threadIdx.x;
    float v;
    if (n < 32)        v = Wf[(size_t)k * 32 + n];
    else if (n < 64)   v = Wg[(size_t)k * 32 + n - 32] * LOG2E;
    else if (n < 320)  v = Wh[(size_t)k * 256 + n - 64];
    else               v = Wv[(size_t)k * 256 + n - 320];
    wT[(size_t)n * 256 + k] = f2bf(v);
}

// ---------------------------------------------------------------------------
// proj: Y[16384,320] = x @ [Wf|Wg|Wh] + bias, bf16 MFMA, no LDS.
// block = 32 rows; wave w = cols w*80..+79 (5 n-tiles).
// cols 0..63 -> fg row-major; cols 64..319 -> hmt channel-major (8B stores).
// ---------------------------------------------------------------------------
__global__ __launch_bounds__(256) void proj_mfma(
    const float* __restrict__ x, const u16* __restrict__ wT,
    const float* __restrict__ bfv, const float* __restrict__ bgv,
    const float* __restrict__ bhv,
    u16* __restrict__ fg, u16* __restrict__ hmt)
{
    const int t    = threadIdx.x;
    const int w    = t >> 6;
    const int lane = t & 63;
    const int quad = lane >> 4;
    const int l16  = lane & 15;
    const int m0   = blockIdx.x * 32;
    const int wb   = w * 80;

    f32x4 acc[2][5];
#pragma unroll
    for (int mt = 0; mt < 2; ++mt)
#pragma unroll
        for (int nt = 0; nt < 5; ++nt)
#pragma unroll
            for (int r = 0; r < 4; ++r) acc[mt][nt][r] = 0.f;

#pragma unroll 2
    for (int ks = 0; ks < 8; ++ks) {
        bf16x8 afrag[2];
#pragma unroll
        for (int mt = 0; mt < 2; ++mt) {
            const float* xp = x + (size_t)(m0 + mt * 16 + l16) * 256 +
                              ks * 32 + quad * 8;
            float4 a0 = *reinterpret_cast<const float4*>(xp);
            float4 a1 = *reinterpret_cast<const float4*>(xp + 4);
            afrag[mt] = cvt8(a0, a1);
        }
#pragma unroll
        for (int nt = 0; nt < 5; ++nt) {
            bf16x8 bfrag = *reinterpret_cast<const bf16x8*>(
                wT + (size_t)(wb + nt * 16 + l16) * 256 + ks * 32 + quad * 8);
#pragma unroll
            for (int mt = 0; mt < 2; ++mt)
                acc[mt][nt] = __builtin_amdgcn_mfma_f32_16x16x32_bf16(
                    afrag[mt], bfrag, acc[mt][nt], 0, 0, 0);
        }
    }

    const int bb   = m0 >> 12;
    const int npix = m0 & 4095;
#pragma unroll
    for (int nt = 0; nt < 5; ++nt) {
        int col = wb + nt * 16 + l16;
        if (col < 64) {
            float bias = (col < 32) ? bfv[col] : bgv[col - 32] * LOG2E;
#pragma unroll
            for (int mt = 0; mt < 2; ++mt) {
                int row = m0 + mt * 16 + quad * 4;
#pragma unroll
                for (int r = 0; r < 4; ++r)
                    fg[(size_t)(row + r) * 64 + col] =
                        f2bf(acc[mt][nt][r] + bias);
            }
        } else {
            int c = col - 64;
            float bias = bhv[c];
#pragma unroll
            for (int mt = 0; mt < 2; ++mt) {
                int n0 = npix + mt * 16 + quad * 4;
                ushort4 hv;
                hv.x = f2bf(acc[mt][nt][0] + bias);
                hv.y = f2bf(acc[mt][nt][1] + bias);
                hv.z = f2bf(acc[mt][nt][2] + bias);
                hv.w = f2bf(acc[mt][nt][3] + bias);
                *reinterpret_cast<ushort4*>(
                    hmt + ((size_t)bb * 256 + c) * 4096 + n0) = hv;
            }
        }
    }
}

// ---------------------------------------------------------------------------
// Flash attention v6 (register-lean):
//  64-key tiles (nkt = 64>>ksl per block). F in REGISTERS (4 B-frags,
//  next-tile prefetched during PV). V staged to LDS via global_load_lds
//  (zero VGPR) in wave-local swizzled chunks. P in LDS [kblk][row][8].
//  LDS = 40960 B (V 32K + P 8K; lfin reuses P) -> 4 blocks/CU.
//  Regs ~ 64 acc + ~80 -> 3-4 waves/SIMD (was 2: vbr removal).
// ---------------------------------------------------------------------------
__global__ __launch_bounds__(256) void attn6(
    const u16* __restrict__ fg, const u16* __restrict__ hmt,
    u16* __restrict__ obf, float* __restrict__ lpart, int ksl)
{
    __shared__ u16 vt[32 * 512];  // 32 chunks of [quad][l16][8] (1 KB each)
    __shared__ u16 pl[4096];      // P: [kblk(8)][row(64)][8]

    const int t    = threadIdx.x;
    const int w    = t >> 6;
    const int lane = t & 63;
    const int quad = lane >> 4;
    const int l16  = lane & 15;

    int b, qt, ks;
    if (ksl == 2) {
        const int u   = blockIdx.x;
        const int xcd = u & 7;
        b = xcd >> 1;
        const int v = ((u >> 3) << 1) | (xcd & 1);   // 0..255
        qt = v >> 2;
        ks = v & 3;
    } else if (ksl == 1) {
        const int u   = blockIdx.x;
        const int xcd = u & 7;
        b = xcd >> 1;
        const int v = ((u >> 3) << 1) | (xcd & 1);   // 0..127
        qt = v >> 1;
        ks = v & 1;
    } else {
        ks = 0;
        qt = blockIdx.x & 63;
        b  = blockIdx.x >> 6;
    }
    const int nkt = 64 >> ksl;          // 64-key tiles
    const int kt0 = ks * nkt;

    const size_t fg_base = (size_t)b * 4096 * 64;
    const size_t hm_base = (size_t)b * 256 * 4096;

    // G A-frag (queries w*16..+15, pre-scaled by log2e)
    const bf16x8 gfrag = *reinterpret_cast<const bf16x8*>(
        fg + fg_base + (size_t)(qt * 64 + w * 16 + l16) * 64 + 32 + quad * 8);

    f32x4 oacc[4][4];
#pragma unroll
    for (int mt = 0; mt < 4; ++mt)
#pragma unroll
        for (int nt = 0; nt < 4; ++nt)
#pragma unroll
            for (int r = 0; r < 4; ++r) oacc[mt][nt][r] = 0.f;

    float lsum[4] = {0.f, 0.f, 0.f, 0.f};
    const f32x4 zero4 = {0.f, 0.f, 0.f, 0.f};

    // prologue: F(kt0) B-frags into registers (keys ct*16+l16, ch quad*8)
    bf16x8 fcur[4], fnext[4];
#pragma unroll
    for (int ct = 0; ct < 4; ++ct)
        fcur[ct] = *reinterpret_cast<const bf16x8*>(
            fg + fg_base + (size_t)(kt0 * 64 + ct * 16 + l16) * 64 + quad * 8);

    for (int it = 0; it < nkt; ++it) {
        const int kt = kt0 + it;
        __syncthreads();   // B1: vt/pl consumed by prev PV

        // stage V(kt): 8 chunks/wave. chunk (nt,kh): lane (q,l) supplies
        // hmt[ch = w*64+nt*16+l][key = kt*64 + kh*32 + q*8 ..+7]
#pragma unroll
        for (int nt = 0; nt < 4; ++nt)
#pragma unroll
            for (int kh = 0; kh < 2; ++kh) {
                const u16* gp = hmt + hm_base +
                    (size_t)(w * 64 + nt * 16 + l16) * 4096 +
                    kt * 64 + kh * 32 + quad * 8;
                ASYNC_CP16(gp, &vt[(((w * 4 + nt) * 2 + kh) << 9)]);
            }

        // prefetch F(kt+1) into regs (in flight through S+exp, used next iter)
        if (it + 1 < nkt) {
#pragma unroll
            for (int ct = 0; ct < 4; ++ct)
                fnext[ct] = *reinterpret_cast<const bf16x8*>(
                    fg + fg_base +
                    (size_t)((kt + 1) * 64 + ct * 16 + l16) * 64 + quad * 8);
        }

        // ---- S = G @ F^T from registers (no waits) ----
        f32x4 sacc[4];
#pragma unroll
        for (int ct = 0; ct < 4; ++ct)
            sacc[ct] = __builtin_amdgcn_mfma_f32_16x16x32_bf16(
                gfrag, fcur[ct], zero4, 0, 0, 0);

        // ---- p = exp2(s'), write P, accumulate l ----
#pragma unroll
        for (int ct = 0; ct < 4; ++ct) {
#pragma unroll
            for (int r = 0; r < 4; ++r) {
                float p = __builtin_amdgcn_exp2f(sacc[ct][r]);
                lsum[r] += p;
                int row = w * 16 + quad * 4 + r;
                int key = ct * 16 + l16;
                pl[(key >> 3) * 512 + row * 8 + (key & 7)] = f2bf(p);
            }
        }
        __syncthreads();   // B2: publish P; drains V(kt) + F(kt+1)

        // ---- O += P @ V  (wave w: cols w*64..+63) ----
#pragma unroll
        for (int kh = 0; kh < 2; ++kh) {
            bf16x8 pa[4];
#pragma unroll
            for (int mt = 0; mt < 4; ++mt)
                pa[mt] = *reinterpret_cast<const bf16x8*>(
                    &pl[(kh * 4 + quad) * 512 + (mt * 16 + l16) * 8]);
#pragma unroll
            for (int nt = 0; nt < 4; ++nt) {
                bf16x8 vb = *reinterpret_cast<const bf16x8*>(
                    &vt[(((w * 4 + nt) * 2 + kh) << 9) +
                        (quad * 16 + l16) * 8]);
#pragma unroll
                for (int mt = 0; mt < 4; ++mt)
                    oacc[mt][nt] = __builtin_amdgcn_mfma_f32_16x16x32_bf16(
                        pa[mt], vb, oacc[mt][nt], 0, 0, 0);
            }
        }

#pragma unroll
        for (int ct = 0; ct < 4; ++ct) fcur[ct] = fnext[ct];
    }

    // ---- epilogue: reduce l, share via pl-reuse, swizzled bf16 store ----
    __syncthreads();                     // last PV's pl reads done
    float* lfin = (float*)pl;            // reuse P buffer
#pragma unroll
    for (int r = 0; r < 4; ++r) {
        float s = lsum[r];
        s += __shfl_xor(s, 1);
        s += __shfl_xor(s, 2);
        s += __shfl_xor(s, 4);
        s += __shfl_xor(s, 8);
        lsum[r] = s;
    }
    if (l16 == 0) {
#pragma unroll
        for (int r = 0; r < 4; ++r) {
            lfin[w * 16 + quad * 4 + r] = lsum[r];
            lpart[((size_t)ks << 14) + b * 4096 + qt * 64 + w * 16 +
                  quad * 4 + r] = lsum[r];
        }
    }
    __syncthreads();

#pragma unroll
    for (int mt = 0; mt < 4; ++mt) {
        f32x4 lv = *reinterpret_cast<const f32x4*>(&lfin[mt * 16 + quad * 4]);
        float inv[4];
#pragma unroll
        for (int r = 0; r < 4; ++r) inv[r] = 1.f / lv[r];
        const int row16 = b * 256 + qt * 4 + mt;
#pragma unroll
        for (int nt = 0; nt < 4; ++nt) {
            int ksc = w * 2 + (nt >> 1);
            int qc  = (nt & 1) * 2 + (l16 >> 3);
            u16* op = obf + ((size_t)ks << 22) +
                (((size_t)row16 * 8 + ksc) << 9) + (qc << 7) + (l16 & 7);
#pragma unroll
            for (int r = 0; r < 4; ++r)
                op[(quad * 4 + r) * 8] = f2bf(oacc[mt][nt][r] * inv[r]);
        }
    }
}

// ---------------------------------------------------------------------------
// final: out = x + (sum_s wgt_s * obf[s]) @ Wv + bv,  wgt_s = l_s / sum l.
// obf fragment swizzle -> per-lane 16B reads are fully coalesced (1 KB/instr)
// so no LDS, no barrier. block = 32 rows; wave w = cols w*64..+63.
// ---------------------------------------------------------------------------
__global__ __launch_bounds__(256) void final_mfma4(
    const u16* __restrict__ obf, const float* __restrict__ lpart, int S,
    const u16* __restrict__ wT, const float* __restrict__ bvv,
    const float* __restrict__ x, float* __restrict__ out)
{
    const int t    = threadIdx.x;
    const int w    = t >> 6;
    const int lane = t & 63;
    const int quad = lane >> 4;
    const int l16  = lane & 15;
    const int m0   = blockIdx.x * 32;
    const int wb   = w * 64;

    float wgt[2][4];
#pragma unroll
    for (int mt = 0; mt < 2; ++mt) {
        int row = m0 + mt * 16 + l16;
        float ls[4];
        float tot = 0.f;
        for (int s = 0; s < S; ++s) {
            ls[s] = lpart[(size_t)s * 16384 + row];
            tot += ls[s];
        }
        float inv = 1.f / tot;
        for (int s = 0; s < S; ++s) wgt[mt][s] = ls[s] * inv;
    }

    f32x4 acc[2][4];
#pragma unroll
    for (int mt = 0; mt < 2; ++mt)
#pragma unroll
        for (int nt = 0; nt < 4; ++nt)
#pragma unroll
            for (int r = 0; r < 4; ++r) acc[mt][nt][r] = 0.f;

#pragma unroll 2
    for (int ks = 0; ks < 8; ++ks) {
        bf16x8 afrag[2];
#pragma unroll
        for (int mt = 0; mt < 2; ++mt) {
            size_t chunk = ((size_t)((m0 >> 4) + mt) * 8 + ks) << 9;
            float f[8] = {0.f, 0.f, 0.f, 0.f, 0.f, 0.f, 0.f, 0.f};
            for (int s = 0; s < S; ++s) {
                bf16x8 v = *reinterpret_cast<const bf16x8*>(
                    obf + ((size_t)s << 22) + chunk + (quad * 16 + l16) * 8);
                float ww = wgt[mt][s];
#pragma unroll
                for (int j = 0; j < 8; ++j) f[j] = fmaf(ww, bf2f(v[j]), f[j]);
            }
            bf16x8 a;
#pragma unroll
            for (int j = 0; j < 8; ++j) a[j] = (short)f2bf(f[j]);
            afrag[mt] = a;
        }
#pragma unroll
        for (int nt = 0; nt < 4; ++nt) {
            bf16x8 bfrag = *reinterpret_cast<const bf16x8*>(
                wT + (size_t)(320 + wb + nt * 16 + l16) * 256 +
                ks * 32 + quad * 8);
#pragma unroll
            for (int mt = 0; mt < 2; ++mt)
                acc[mt][nt] = __builtin_amdgcn_mfma_f32_16x16x32_bf16(
                    afrag[mt], bfrag, acc[mt][nt], 0, 0, 0);
        }
    }

#pragma unroll
    for (int nt = 0; nt < 4; ++nt) {
        int col = wb + nt * 16 + l16;
        float bias = bvv[col];
#pragma unroll
        for (int mt = 0; mt < 2; ++mt) {
            int row = m0 + mt * 16 + quad * 4;
#pragma unroll
            for (int r = 0; r < 4; ++r) {
                size_t off = (size_t)(row + r) * 256 + col;
                out[off] = acc[mt][nt][r] + bias + x[off];
            }
        }
    }
}

// ---------------------------------------------------------------------------
extern "C" void kernel_launch(void* const* d_in, const int* in_sizes, int n_in,
                              void* d_out, int out_size, void* d_ws, size_t ws_size,
                              hipStream_t stream)
{
    const float* x  = (const float*)d_in[0];
    const float* Wf = (const float*)d_in[1];
    const float* bf = (const float*)d_in[2];
    const float* Wg = (const float*)d_in[3];
    const float* bg = (const float*)d_in[4];
    const float* Wh = (const float*)d_in[5];
    const float* bh = (const float*)d_in[6];
    const float* Wv = (const float*)d_in[7];
    const float* bv = (const float*)d_in[8];
    float* out = (float*)d_out;

    const int M = 16384;

    const size_t base_b = (size_t)M * 64 * 2 + (size_t)4 * 256 * 4096 * 2 +
                          (size_t)576 * 256 * 2;
    const size_t per_s  = (size_t)M * 4 + (size_t)M * 256 * 2;
    int ksl = 0;
    if (ws_size >= base_b + 4 * per_s)      ksl = 2;
    else if (ws_size >= base_b + 2 * per_s) ksl = 1;
    const int S = 1 << ksl;

    u16*   fgbuf = (u16*)d_ws;
    u16*   hmt   = fgbuf + (size_t)M * 64;
    u16*   wT    = hmt + (size_t)4 * 256 * 4096;
    float* lpart = (float*)(wT + (size_t)576 * 256);
    u16*   obf   = (u16*)(lpart + (size_t)S * M);

    dim3 blk(256);

    prep_w<<<dim3(576), blk, 0, stream>>>(Wf, Wg, Wh, Wv, wT);
    proj_mfma<<<dim3(M / 32), blk, 0, stream>>>(x, wT, bf, bg, bh, fgbuf, hmt);
    attn6<<<dim3(256 * S), blk, 0, stream>>>(fgbuf, hmt, obf, lpart, ksl);
    final_mfma4<<<dim3(M / 32), blk, 0, stream>>>(
        obf, lpart, S, wT, bv, x, out);
}

// Round 10
// 199.340 us; speedup vs baseline: 1.1729x; 1.1729x over previous
//
#include <hip/hip_runtime.h>
#include <math.h>

// B=4, H=W=64, C=256, Ck=32, N=4096, M=B*N=16384
// ws: fg bf16 [16384][64] (f=cols0..31, g=cols32..63, g pre-scaled by log2e)
//   | hmt bf16 [4][256][4096] (channel-major)
//   | wT bf16 [576][256] (0..31 Wf^T, 32..63 Wg^T*log2e, 64..319 Wh^T, 320..575 Wv^T)
//   | lpart f32 [S][16384]
//   | obf bf16 [S][1<<22]  -- FRAGMENT-SWIZZLED: chunk = row16*8 + (col>>5),
//       element (row,col) at chunk*512 + ((col>>3)&3)*128 + (row&15)*8 + (col&7)

typedef unsigned short u16;
typedef __attribute__((ext_vector_type(8))) short  bf16x8;
typedef __attribute__((ext_vector_type(4))) float  f32x4;

__device__ inline u16 f2bf(float x) {
    unsigned u = __float_as_uint(x);
    unsigned r = (u + 0x7fffu + ((u >> 16) & 1u)) >> 16;
    return (u16)r;
}

__device__ inline float bf2f(short s) {
    return __uint_as_float(((unsigned)(u16)s) << 16);
}

__device__ inline bf16x8 cvt8(float4 a, float4 b) {
    bf16x8 r;
    r[0] = (short)f2bf(a.x); r[1] = (short)f2bf(a.y);
    r[2] = (short)f2bf(a.z); r[3] = (short)f2bf(a.w);
    r[4] = (short)f2bf(b.x); r[5] = (short)f2bf(b.y);
    r[6] = (short)f2bf(b.z); r[7] = (short)f2bf(b.w);
    return r;
}

#define ASYNC_CP16(gp, lp)                                                     \
    __builtin_amdgcn_global_load_lds(                                          \
        (const __attribute__((address_space(1))) void*)(gp),                   \
        (__attribute__((address_space(3))) void*)(lp), 16, 0, 0)

#define LOG2E 1.4426950408889634f

// ---------------------------------------------------------------------------
// prep: pack weights transposed to bf16.  wT[n][k], n = concat col index.
// ---------------------------------------------------------------------------
__global__ __launch_bounds__(256) void prep_w(
    const float* __restrict__ Wf, const float* __restrict__ Wg,
    const float* __restrict__ Wh, const float* __restrict__ Wv,
    u16* __restrict__ wT)
{
    const int n = blockIdx.x;
    const int k = threadIdx.x;
    float v;
    if (n < 32)        v = Wf[(size_t)k * 32 + n];
    else if (n < 64)   v = Wg[(size_t)k * 32 + n - 32] * LOG2E;
    else if (n < 320)  v = Wh[(size_t)k * 256 + n - 64];
    else               v = Wv[(size_t)k * 256 + n - 320];
    wT[(size_t)n * 256 + k] = f2bf(v);
}

// ---------------------------------------------------------------------------
// proj v2: Y[16384,320] = x @ [Wf|Wg|Wh] + bias, bf16 MFMA.
// 16 rows/block (grid 1024, ~8 blocks/CU for latency hiding). x tile
// (16x256 fp32) staged to LDS with fully-coalesced float4 reads; pad-268
// rows -> <=2-way bank conflicts on b128 frag reads. Single stage, no K-loop
// staging. Wave w = cols w*80..+79 (5 n-tiles).
// ---------------------------------------------------------------------------
__global__ __launch_bounds__(256) void proj_mfma2(
    const float* __restrict__ x, const u16* __restrict__ wT,
    const float* __restrict__ bfv, const float* __restrict__ bgv,
    const float* __restrict__ bhv,
    u16* __restrict__ fg, u16* __restrict__ hmt)
{
    __shared__ float xl[16 * 268];   // 16 rows, stride 268 (1072 B)

    const int t    = threadIdx.x;
    const int w    = t >> 6;
    const int lane = t & 63;
    const int quad = lane >> 4;
    const int l16  = lane & 15;
    const int m0   = blockIdx.x * 16;
    const int wb   = w * 80;

    // stage x tile: 1024 float4, 4/thread, coalesced (64 lanes = 1 KB)
#pragma unroll
    for (int i = 0; i < 4; ++i) {
        int idx = i * 256 + t;
        int row = idx >> 6;
        int c4  = (idx & 63) << 2;
        float4 v = *reinterpret_cast<const float4*>(
            x + (size_t)(m0 + row) * 256 + c4);
        *reinterpret_cast<float4*>(&xl[row * 268 + c4]) = v;
    }
    __syncthreads();

    f32x4 acc[5];
#pragma unroll
    for (int nt = 0; nt < 5; ++nt)
#pragma unroll
        for (int r = 0; r < 4; ++r) acc[nt][r] = 0.f;

#pragma unroll 2
    for (int ks = 0; ks < 8; ++ks) {
        const float* xp = &xl[l16 * 268 + ks * 32 + quad * 8];
        float4 a0 = *reinterpret_cast<const float4*>(xp);
        float4 a1 = *reinterpret_cast<const float4*>(xp + 4);
        bf16x8 afrag = cvt8(a0, a1);
#pragma unroll
        for (int nt = 0; nt < 5; ++nt) {
            bf16x8 bfrag = *reinterpret_cast<const bf16x8*>(
                wT + (size_t)(wb + nt * 16 + l16) * 256 + ks * 32 + quad * 8);
            acc[nt] = __builtin_amdgcn_mfma_f32_16x16x32_bf16(
                afrag, bfrag, acc[nt], 0, 0, 0);
        }
    }

    const int bb   = m0 >> 12;
    const int npix = m0 & 4095;
#pragma unroll
    for (int nt = 0; nt < 5; ++nt) {
        int col = wb + nt * 16 + l16;
        if (col < 64) {
            float bias = (col < 32) ? bfv[col] : bgv[col - 32] * LOG2E;
            int row = m0 + quad * 4;
#pragma unroll
            for (int r = 0; r < 4; ++r)
                fg[(size_t)(row + r) * 64 + col] = f2bf(acc[nt][r] + bias);
        } else {
            int c = col - 64;
            float bias = bhv[c];
            int n0 = npix + quad * 4;
            ushort4 hv;
            hv.x = f2bf(acc[nt][0] + bias);
            hv.y = f2bf(acc[nt][1] + bias);
            hv.z = f2bf(acc[nt][2] + bias);
            hv.w = f2bf(acc[nt][3] + bias);
            *reinterpret_cast<ushort4*>(
                hmt + ((size_t)bb * 256 + c) * 4096 + n0) = hv;
        }
    }
}

// ---------------------------------------------------------------------------
// Flash attention (best-known config): S=2 split-K, 128-key tiles, V in
// registers, F staged via global_load_lds dbuf, P in conflict-free LDS,
// XCD batch-pair swizzle, exp2 softmax, fragment-swizzled obf output.
// ---------------------------------------------------------------------------
__global__ __launch_bounds__(256) void attn5(
    const u16* __restrict__ fg, const u16* __restrict__ hmt,
    u16* __restrict__ obf, float* __restrict__ lpart, int ksl)
{
    __shared__ u16 fl[2][4096];   // F dbuf: [ct(8)][quad(4)][l16(16)][8]
    __shared__ u16 pl[8192];      // P: [kblk(16)][row(64)][8]
    __shared__ float lfin[64];

    const int t    = threadIdx.x;
    const int w    = t >> 6;
    const int lane = t & 63;
    const int quad = lane >> 4;
    const int l16  = lane & 15;

    int b, qt, ks;
    if (ksl == 1) {
        const int u   = blockIdx.x;
        const int xcd = u & 7;
        b = xcd >> 1;
        const int v = ((u >> 3) << 1) | (xcd & 1);   // 0..127
        qt = v >> 1;
        ks = v & 1;
    } else {
        ks = 0;
        qt = blockIdx.x & 63;
        b  = blockIdx.x >> 6;
    }
    const int nkt = 32 >> ksl;
    const int kt0 = ks * nkt;

    const size_t fg_base = (size_t)b * 4096 * 64;
    const size_t hm_base = (size_t)b * 256 * 4096;

    const bf16x8 gfrag = *reinterpret_cast<const bf16x8*>(
        fg + fg_base + (size_t)(qt * 64 + w * 16 + l16) * 64 + 32 + quad * 8);

    f32x4 oacc[4][4];
#pragma unroll
    for (int mt = 0; mt < 4; ++mt)
#pragma unroll
        for (int nt = 0; nt < 4; ++nt)
#pragma unroll
            for (int r = 0; r < 4; ++r) oacc[mt][nt][r] = 0.f;

    float lsum[4] = {0.f, 0.f, 0.f, 0.f};
    const f32x4 zero4 = {0.f, 0.f, 0.f, 0.f};

    {
        const u16* gp = fg + fg_base +
            (size_t)(kt0 * 128 + (2 * w) * 16 + l16) * 64 + quad * 8;
        ASYNC_CP16(gp, &fl[0][(2 * w) * 512]);
        ASYNC_CP16(gp + 16 * 64, &fl[0][(2 * w + 1) * 512]);
    }

    for (int it = 0; it < nkt; ++it) {
        const int kt  = kt0 + it;
        const int buf = it & 1;
        __syncthreads();   // B1: P consumed by prev PV; F(kt) resident

        bf16x8 vbr[4][4];
#pragma unroll
        for (int nt = 0; nt < 4; ++nt)
#pragma unroll
            for (int kh = 0; kh < 4; ++kh)
                vbr[nt][kh] = *reinterpret_cast<const bf16x8*>(
                    hmt + hm_base + (size_t)(w * 64 + nt * 16 + l16) * 4096 +
                    kt * 128 + kh * 32 + quad * 8);

        if (it + 1 < nkt) {
            const u16* gp = fg + fg_base +
                (size_t)((kt + 1) * 128 + (2 * w) * 16 + l16) * 64 + quad * 8;
            ASYNC_CP16(gp, &fl[buf ^ 1][(2 * w) * 512]);
            ASYNC_CP16(gp + 16 * 64, &fl[buf ^ 1][(2 * w + 1) * 512]);
        }

        f32x4 sacc[8];
#pragma unroll
        for (int ct = 0; ct < 8; ++ct) {
            bf16x8 fb = *reinterpret_cast<const bf16x8*>(
                &fl[buf][ct * 512 + quad * 128 + l16 * 8]);
            sacc[ct] = __builtin_amdgcn_mfma_f32_16x16x32_bf16(
                gfrag, fb, zero4, 0, 0, 0);
        }

#pragma unroll
        for (int ct = 0; ct < 8; ++ct) {
#pragma unroll
            for (int r = 0; r < 4; ++r) {
                float p = __builtin_amdgcn_exp2f(sacc[ct][r]);
                lsum[r] += p;
                int row = w * 16 + quad * 4 + r;
                int key = ct * 16 + l16;
                pl[(key >> 3) * 512 + row * 8 + (key & 7)] = f2bf(p);
            }
        }
        __syncthreads();   // B2: publish P; drains V(kt) + F(kt+1)

#pragma unroll
        for (int kh = 0; kh < 4; ++kh) {
            bf16x8 pa[4];
#pragma unroll
            for (int mt = 0; mt < 4; ++mt)
                pa[mt] = *reinterpret_cast<const bf16x8*>(
                    &pl[(kh * 4 + quad) * 512 + (mt * 16 + l16) * 8]);
#pragma unroll
            for (int nt = 0; nt < 4; ++nt)
#pragma unroll
                for (int mt = 0; mt < 4; ++mt)
                    oacc[mt][nt] = __builtin_amdgcn_mfma_f32_16x16x32_bf16(
                        pa[mt], vbr[nt][kh], oacc[mt][nt], 0, 0, 0);
        }
    }

    // ---- epilogue: reduce l, share, store normalized bf16 SWIZZLED ----
#pragma unroll
    for (int r = 0; r < 4; ++r) {
        float s = lsum[r];
        s += __shfl_xor(s, 1);
        s += __shfl_xor(s, 2);
        s += __shfl_xor(s, 4);
        s += __shfl_xor(s, 8);
        lsum[r] = s;
    }
    if (l16 == 0) {
#pragma unroll
        for (int r = 0; r < 4; ++r) {
            lfin[w * 16 + quad * 4 + r] = lsum[r];
            lpart[((size_t)ks << 14) + b * 4096 + qt * 64 + w * 16 +
                  quad * 4 + r] = lsum[r];
        }
    }
    __syncthreads();

#pragma unroll
    for (int mt = 0; mt < 4; ++mt) {
        f32x4 lv = *reinterpret_cast<const f32x4*>(&lfin[mt * 16 + quad * 4]);
        float inv[4];
#pragma unroll
        for (int r = 0; r < 4; ++r) inv[r] = 1.f / lv[r];
        const int row16 = b * 256 + qt * 4 + mt;
#pragma unroll
        for (int nt = 0; nt < 4; ++nt) {
            int ksc = w * 2 + (nt >> 1);
            int qc  = (nt & 1) * 2 + (l16 >> 3);
            u16* op = obf + ((size_t)ks << 22) +
                (((size_t)row16 * 8 + ksc) << 9) + (qc << 7) + (l16 & 7);
#pragma unroll
            for (int r = 0; r < 4; ++r)
                op[(quad * 4 + r) * 8] = f2bf(oacc[mt][nt][r] * inv[r]);
        }
    }
}

// ---------------------------------------------------------------------------
// final v2: out = x + (sum_s wgt_s * obf[s]) @ Wv + bv,  wgt_s = l_s/sum l.
// 16 rows/block (grid 1024). obf staged via coalesced global_load_lds
// (fragment swizzle -> contiguous 1 KB chunks). S <= 2.
// ---------------------------------------------------------------------------
__global__ __launch_bounds__(256) void final_mfma5(
    const u16* __restrict__ obf, const float* __restrict__ lpart, int S,
    const u16* __restrict__ wT, const float* __restrict__ bvv,
    const float* __restrict__ x, float* __restrict__ out)
{
    __shared__ u16 ol[8192];   // [s(<=2)][ks(8)] chunks of [quad][l16][8]

    const int t    = threadIdx.x;
    const int w    = t >> 6;
    const int lane = t & 63;
    const int quad = lane >> 4;
    const int l16  = lane & 15;
    const int m0   = blockIdx.x * 16;
    const int wb   = w * 64;

    // stage obf chunks: S*8 issues (S*2 per wave), each 1 KB contiguous
    const int ni = S * 2;
    for (int i = 0; i < ni; ++i) {
        int gi = w * ni + i;           // 0..S*8-1
        int s  = gi >> 3;
        int ks = gi & 7;
        const u16* gp = obf + ((size_t)s << 22) +
            (((size_t)(m0 >> 4) * 8 + ks) << 9) + lane * 8;
        ASYNC_CP16(gp, &ol[gi * 512]);
    }

    float wgt[2];
    {
        int row = m0 + l16;
        float l0 = lpart[row];
        float l1 = (S > 1) ? lpart[16384 + row] : 0.f;
        float inv = 1.f / (l0 + l1);
        wgt[0] = l0 * inv;
        wgt[1] = l1 * inv;
    }
    __syncthreads();

    f32x4 acc[4];
#pragma unroll
    for (int nt = 0; nt < 4; ++nt)
#pragma unroll
        for (int r = 0; r < 4; ++r) acc[nt][r] = 0.f;

#pragma unroll 2
    for (int ks = 0; ks < 8; ++ks) {
        bf16x8 afrag;
        {
            bf16x8 v0 = *reinterpret_cast<const bf16x8*>(
                &ol[ks * 512 + (quad * 16 + l16) * 8]);
            if (S > 1) {
                bf16x8 v1 = *reinterpret_cast<const bf16x8*>(
                    &ol[(8 + ks) * 512 + (quad * 16 + l16) * 8]);
#pragma unroll
                for (int j = 0; j < 8; ++j)
                    afrag[j] = (short)f2bf(
                        fmaf(wgt[0], bf2f(v0[j]), wgt[1] * bf2f(v1[j])));
            } else {
                afrag = v0;
            }
        }
#pragma unroll
        for (int nt = 0; nt < 4; ++nt) {
            bf16x8 bfrag = *reinterpret_cast<const bf16x8*>(
                wT + (size_t)(320 + wb + nt * 16 + l16) * 256 +
                ks * 32 + quad * 8);
            acc[nt] = __builtin_amdgcn_mfma_f32_16x16x32_bf16(
                afrag, bfrag, acc[nt], 0, 0, 0);
        }
    }

#pragma unroll
    for (int nt = 0; nt < 4; ++nt) {
        int col = wb + nt * 16 + l16;
        float bias = bvv[col];
        int row = m0 + quad * 4;
#pragma unroll
        for (int r = 0; r < 4; ++r) {
            size_t off = (size_t)(row + r) * 256 + col;
            out[off] = acc[nt][r] + bias + x[off];
        }
    }
}

// ---------------------------------------------------------------------------
extern "C" void kernel_launch(void* const* d_in, const int* in_sizes, int n_in,
                              void* d_out, int out_size, void* d_ws, size_t ws_size,
                              hipStream_t stream)
{
    const float* x  = (const float*)d_in[0];
    const float* Wf = (const float*)d_in[1];
    const float* bf = (const float*)d_in[2];
    const float* Wg = (const float*)d_in[3];
    const float* bg = (const float*)d_in[4];
    const float* Wh = (const float*)d_in[5];
    const float* bh = (const float*)d_in[6];
    const float* Wv = (const float*)d_in[7];
    const float* bv = (const float*)d_in[8];
    float* out = (float*)d_out;

    const int M = 16384;

    const size_t base_b = (size_t)M * 64 * 2 + (size_t)4 * 256 * 4096 * 2 +
                          (size_t)576 * 256 * 2;
    const size_t per_s  = (size_t)M * 4 + (size_t)M * 256 * 2;
    int ksl = (ws_size >= base_b + 2 * per_s) ? 1 : 0;   // S=2 preferred
    const int S = 1 << ksl;

    u16*   fgbuf = (u16*)d_ws;
    u16*   hmt   = fgbuf + (size_t)M * 64;
    u16*   wT    = hmt + (size_t)4 * 256 * 4096;
    float* lpart = (float*)(wT + (size_t)576 * 256);
    u16*   obf   = (u16*)(lpart + (size_t)S * M);

    dim3 blk(256);

    prep_w<<<dim3(576), blk, 0, stream>>>(Wf, Wg, Wh, Wv, wT);
    proj_mfma2<<<dim3(M / 16), blk, 0, stream>>>(x, wT, bf, bg, bh, fgbuf, hmt);
    attn5<<<dim3(256 * S), blk, 0, stream>>>(fgbuf, hmt, obf, lpart, ksl);
    final_mfma5<<<dim3(M / 16), blk, 0, stream>>>(
        obf, lpart, S, wT, bv, x, out);
}